// Round 2
// baseline (574.651 us; speedup 1.0000x reference)
//
#include <hip/hip_runtime.h>
#include <hip/hip_bf16.h>
#include <stdint.h>

#define HW 65536
#define BATCH 64
#define KTOP 200
#define TLOW 16.0f   // candidate pre-filter: P(diff >= 16) ~ 4.6% for 2*chi2(3);
                     // exact whenever per-batch candidate count >= KTOP (fallback otherwise)

// ---------------------------------------------------------------------------
// Kernel 1: fused diff + threshold compaction. Full-device, pure-read.
// Each thread: one float4 per channel. Values >= TLOW are stream-compacted
// into cand[b][*] via wave-ballot + one atomic per wave per component.
// ---------------------------------------------------------------------------
__global__ __launch_bounds__(256) void fused_diff_compact(
    const float* __restrict__ pred,
    const float* __restrict__ target,
    float* __restrict__ cand,
    uint32_t* __restrict__ cnt)
{
    int n = blockIdx.x * 256 + threadIdx.x;      // float4 index, 0 .. B*HW/4-1
    int b = n >> 14;                             // 16384 float4 per batch
    int i = n & 16383;
    const float4* p = (const float4*)pred;
    const float4* t = (const float4*)target;
    long base = (long)b * 49152 + i;             // 3 * 16384
    float4 p0 = p[base], p1 = p[base + 16384], p2 = p[base + 32768];
    float4 t0 = t[base], t1 = t[base + 16384], t2 = t[base + 32768];

    float d[4];
    {
        float a0 = t0.x - p0.x, a1 = t1.x - p1.x, a2 = t2.x - p2.x;
        d[0] = a0 * a0 + a1 * a1 + a2 * a2;
    }
    {
        float a0 = t0.y - p0.y, a1 = t1.y - p1.y, a2 = t2.y - p2.y;
        d[1] = a0 * a0 + a1 * a1 + a2 * a2;
    }
    {
        float a0 = t0.z - p0.z, a1 = t1.z - p1.z, a2 = t2.z - p2.z;
        d[2] = a0 * a0 + a1 * a1 + a2 * a2;
    }
    {
        float a0 = t0.w - p0.w, a1 = t1.w - p1.w, a2 = t2.w - p2.w;
        d[3] = a0 * a0 + a1 * a1 + a2 * a2;
    }

    float* cb = cand + (long)b * HW;
    const int lane = threadIdx.x & 63;
    #pragma unroll
    for (int j = 0; j < 4; ++j) {
        bool pr = d[j] >= TLOW;
        unsigned long long mask = __ballot(pr);
        if (mask) {                               // wave-uniform
            uint32_t c = (uint32_t)__popcll(mask);
            uint32_t bidx = 0;
            if (lane == 0) bidx = atomicAdd(&cnt[b], c);
            bidx = __shfl(bidx, 0, 64);
            if (pr) {
                uint32_t rank = (uint32_t)__popcll(mask & ((1ull << lane) - 1ull));
                cb[bidx + rank] = d[j];
            }
        }
    }
}

// ---------------------------------------------------------------------------
// Kernel 2: one block (256 thr) per batch. Exact 3-pass radix select of the
// KTOP-th largest over the candidate set (or full recomputed row as fallback
// when candidate count < KTOP), then sum of top-KTOP.
// ---------------------------------------------------------------------------
__global__ __launch_bounds__(256) void select_sum(
    const float* __restrict__ cand,      // may be null -> always fallback
    const uint32_t* __restrict__ cnt,
    const float* __restrict__ pred,
    const float* __restrict__ target,
    float* __restrict__ partials)
{
    __shared__ uint32_t hist[2048];
    __shared__ uint32_t sufx[2048];
    __shared__ float    cls[8192];
    __shared__ uint32_t bcast[2];
    __shared__ uint32_t wtmp[4];
    __shared__ float    wsumS[4];
    __shared__ uint32_t wcntS[4];

    const int b    = blockIdx.x;
    const int tid  = threadIdx.x;
    const int lane = tid & 63;
    const int wave = tid >> 6;

    uint32_t n;
    const float* src = nullptr;
    bool fb = true;
    if (cand) {
        n = cnt[b];
        if (n >= KTOP) { src = cand + (long)b * HW; fb = false; }
    }
    if (fb) n = HW;

    const float* pb = pred   + (long)b * 3 * HW;
    const float* tb = target + (long)b * 3 * HW;

    bool useLds = (!fb && n <= 8192);
    if (useLds) {
        for (uint32_t i = tid; i < n; i += 256) cls[i] = src[i];
    }
    __syncthreads();

    auto getv = [&](uint32_t i) -> float {
        if (useLds) return cls[i];
        if (!fb)    return src[i];
        float a0 = tb[i] - pb[i];
        float a1 = tb[HW + i] - pb[HW + i];
        float a2 = tb[2 * HW + i] - pb[2 * HW + i];
        return a0 * a0 + a1 * a1 + a2 * a2;
    };

    uint32_t k_need = KTOP;
    uint32_t b1 = 0, b2 = 0, b3 = 0;

    #define RUN_PASS(BIN_EXPR, PRED_EXPR, OUT_B)                               \
    {                                                                          \
        for (int i2 = tid; i2 < 2048; i2 += 256) hist[i2] = 0;                 \
        __syncthreads();                                                       \
        for (uint32_t i = tid; i < n; i += 256) {                              \
            uint32_t uv = __float_as_uint(getv(i));                            \
            (void)uv;                                                          \
            if (PRED_EXPR) atomicAdd(&hist[(BIN_EXPR)], 1u);                   \
        }                                                                      \
        __syncthreads();                                                       \
        /* hierarchical inclusive suffix-sum over 2048 bins */                 \
        uint32_t loc[8];                                                       \
        {                                                                      \
            int base8 = tid * 8;                                               \
            uint32_t run = 0;                                                  \
            for (int j = 7; j >= 0; --j) { run += hist[base8 + j]; loc[j] = run; } \
        }                                                                      \
        uint32_t tot = loc[0];                                                 \
        uint32_t scan = tot;                                                   \
        for (int off = 1; off < 64; off <<= 1) {                               \
            uint32_t v = __shfl_down(scan, off, 64);                           \
            if (lane + off < 64) scan += v;                                    \
        }                                                                      \
        if (lane == 0) wtmp[wave] = scan;   /* wave total */                   \
        __syncthreads();                                                       \
        uint32_t wabove = 0;                                                   \
        for (int w = wave + 1; w < 4; ++w) wabove += wtmp[w];                  \
        uint32_t add = (scan - tot) + wabove;                                  \
        {                                                                      \
            int base8 = tid * 8;                                               \
            for (int j = 0; j < 8; ++j) sufx[base8 + j] = loc[j] + add;        \
        }                                                                      \
        __syncthreads();                                                       \
        {                                                                      \
            int base8 = tid * 8;                                               \
            for (int j = 0; j < 8; ++j) {                                      \
                int i2 = base8 + j;                                            \
                uint32_t Si = sufx[i2];                                        \
                uint32_t Sn = (i2 + 1 < 2048) ? sufx[i2 + 1] : 0;              \
                if (Si >= k_need && Sn < k_need) {                             \
                    bcast[0] = (uint32_t)i2;                                   \
                    bcast[1] = k_need - Sn;                                    \
                }                                                              \
            }                                                                  \
        }                                                                      \
        __syncthreads();                                                       \
        OUT_B  = bcast[0];                                                     \
        k_need = bcast[1];                                                     \
        __syncthreads();                                                       \
    }

    RUN_PASS((uv >> 21), true, b1)
    RUN_PASS(((uv >> 10) & 0x7FFu), ((uv >> 21) == b1), b2)
    {
        uint32_t prefix21 = (b1 << 11) | b2;
        RUN_PASS((uv & 0x3FFu), ((uv >> 10) == prefix21), b3)
    }
    #undef RUN_PASS

    const uint32_t T  = (b1 << 21) | (b2 << 10) | b3;
    const float    tv = __uint_as_float(T);

    float    s = 0.0f;
    uint32_t c = 0;
    for (uint32_t i = tid; i < n; i += 256) {
        uint32_t uv = __float_as_uint(getv(i));
        if (uv > T) { s += __uint_as_float(uv); c += 1u; }
    }
    for (int off = 32; off > 0; off >>= 1) {
        s += __shfl_down(s, off, 64);
        c += __shfl_down(c, off, 64);
    }
    if (lane == 0) { wsumS[wave] = s; wcntS[wave] = c; }
    __syncthreads();
    if (tid == 0) {
        float    S = 0.0f;
        uint32_t C = 0;
        for (int w = 0; w < 4; ++w) { S += wsumS[w]; C += wcntS[w]; }
        partials[b] = S + (float)(KTOP - C) * tv;
    }
}

// ---------------------------------------------------------------------------
// Kernel 3: mean of 64 per-batch top-k sums -> scalar
// ---------------------------------------------------------------------------
__global__ void finalize_kernel(const float* __restrict__ partials,
                                float* __restrict__ out)
{
    float v = partials[threadIdx.x];
    for (int off = 32; off > 0; off >>= 1)
        v += __shfl_down(v, off, 64);
    if (threadIdx.x == 0)
        out[0] = v / (float)(BATCH * KTOP);
}

extern "C" void kernel_launch(void* const* d_in, const int* in_sizes, int n_in,
                              void* d_out, int out_size, void* d_ws, size_t ws_size,
                              hipStream_t stream)
{
    const float* pred   = (const float*)d_in[0];
    const float* target = (const float*)d_in[1];
    float* out = (float*)d_out;

    uint32_t* cnt      = (uint32_t*)d_ws;                       // 64 u32
    float*    partials = (float*)((char*)d_ws + 256);           // 64 f32
    float*    cand     = (float*)((char*)d_ws + 512);           // 64*HW f32
    const size_t need  = 512 + (size_t)BATCH * HW * sizeof(float);

    if (ws_size >= need) {
        hipMemsetAsync(cnt, 0, BATCH * sizeof(uint32_t), stream);
        fused_diff_compact<<<4096, 256, 0, stream>>>(pred, target, cand, cnt);
        select_sum<<<BATCH, 256, 0, stream>>>(cand, cnt, pred, target, partials);
    } else {
        select_sum<<<BATCH, 256, 0, stream>>>(nullptr, nullptr, pred, target, partials);
    }
    finalize_kernel<<<1, 64, 0, stream>>>(partials, out);
}

// Round 3
// 41.170 us; speedup vs baseline: 13.9582x; 13.9582x over previous
//
#include <hip/hip_runtime.h>
#include <hip/hip_bf16.h>
#include <stdint.h>

#define HW 65536
#define BATCH 64
#define KTOP 200
#define TLOW 16.0f      // candidate pre-filter: P(diff >= 16) ~ 4.6% for 2*chi2(3);
                        // exact whenever per-batch candidate count >= KTOP (fallback otherwise)
#define CNT_STRIDE 32   // pad per-batch counters to 128 B to kill same-line atomic contention

// ---------------------------------------------------------------------------
// Kernel 1: fused diff + threshold compaction.
// Each block = 1024 elements of ONE batch. Candidates staged in LDS
// (wave-ballot + per-wave LDS atomic), ONE global atomic per block,
// then cooperative coalesced write-out.
// ---------------------------------------------------------------------------
__global__ __launch_bounds__(256) void fused_diff_compact(
    const float* __restrict__ pred,
    const float* __restrict__ target,
    float* __restrict__ cand,
    uint32_t* __restrict__ cnt)
{
    __shared__ float    sbuf[1024];
    __shared__ uint32_t scnt;
    __shared__ uint32_t sbase;

    const int tid  = threadIdx.x;
    const int lane = tid & 63;
    if (tid == 0) scnt = 0;
    __syncthreads();

    const int b   = blockIdx.x >> 6;       // 64 blocks per batch
    const int blk = blockIdx.x & 63;
    const int i   = blk * 256 + tid;       // float4 index within batch [0,16384)

    const float4* p = (const float4*)pred;
    const float4* t = (const float4*)target;
    long base = (long)b * 49152 + i;       // 3 * 16384
    float4 p0 = p[base], p1 = p[base + 16384], p2 = p[base + 32768];
    float4 t0 = t[base], t1 = t[base + 16384], t2 = t[base + 32768];

    float d[4];
    {
        float a0 = t0.x - p0.x, a1 = t1.x - p1.x, a2 = t2.x - p2.x;
        d[0] = a0 * a0 + a1 * a1 + a2 * a2;
    }
    {
        float a0 = t0.y - p0.y, a1 = t1.y - p1.y, a2 = t2.y - p2.y;
        d[1] = a0 * a0 + a1 * a1 + a2 * a2;
    }
    {
        float a0 = t0.z - p0.z, a1 = t1.z - p1.z, a2 = t2.z - p2.z;
        d[2] = a0 * a0 + a1 * a1 + a2 * a2;
    }
    {
        float a0 = t0.w - p0.w, a1 = t1.w - p1.w, a2 = t2.w - p2.w;
        d[3] = a0 * a0 + a1 * a1 + a2 * a2;
    }

    #pragma unroll
    for (int j = 0; j < 4; ++j) {
        bool pr = d[j] >= TLOW;
        unsigned long long mask = __ballot(pr);
        if (mask) {                                   // wave-uniform
            uint32_t c = (uint32_t)__popcll(mask);
            uint32_t wb = 0;
            if (lane == 0) wb = atomicAdd(&scnt, c);  // LDS atomic: on-CU, cheap
            wb = __shfl(wb, 0, 64);
            if (pr) {
                uint32_t rank = (uint32_t)__popcll(mask & ((1ull << lane) - 1ull));
                sbuf[wb + rank] = d[j];
            }
        }
    }
    __syncthreads();

    if (tid == 0) sbase = atomicAdd(&cnt[b * CNT_STRIDE], scnt);  // 1 global atomic/block
    __syncthreads();

    const uint32_t nloc = scnt;
    const uint32_t bs   = sbase;
    float* cb = cand + (long)b * HW;
    for (uint32_t k = tid; k < nloc; k += 256)
        cb[bs + k] = sbuf[k];
}

// ---------------------------------------------------------------------------
// Kernel 2: one block (256 thr) per batch. Exact 3-pass radix select of the
// KTOP-th largest over the candidate set (or full recomputed row as fallback
// when candidate count < KTOP), then sum of top-KTOP.
// ---------------------------------------------------------------------------
__global__ __launch_bounds__(256) void select_sum(
    const float* __restrict__ cand,      // may be null -> always fallback
    const uint32_t* __restrict__ cnt,
    const float* __restrict__ pred,
    const float* __restrict__ target,
    float* __restrict__ partials)
{
    __shared__ uint32_t hist[2048];
    __shared__ uint32_t sufx[2048];
    __shared__ float    cls[8192];
    __shared__ uint32_t bcast[2];
    __shared__ uint32_t wtmp[4];
    __shared__ float    wsumS[4];
    __shared__ uint32_t wcntS[4];

    const int b    = blockIdx.x;
    const int tid  = threadIdx.x;
    const int lane = tid & 63;
    const int wave = tid >> 6;

    uint32_t n;
    const float* src = nullptr;
    bool fb = true;
    if (cand) {
        n = cnt[b * CNT_STRIDE];
        if (n >= KTOP) { src = cand + (long)b * HW; fb = false; }
    }
    if (fb) n = HW;

    const float* pb = pred   + (long)b * 3 * HW;
    const float* tb = target + (long)b * 3 * HW;

    bool useLds = (!fb && n <= 8192);
    if (useLds) {
        for (uint32_t i = tid; i < n; i += 256) cls[i] = src[i];
    }
    __syncthreads();

    auto getv = [&](uint32_t i) -> float {
        if (useLds) return cls[i];
        if (!fb)    return src[i];
        float a0 = tb[i] - pb[i];
        float a1 = tb[HW + i] - pb[HW + i];
        float a2 = tb[2 * HW + i] - pb[2 * HW + i];
        return a0 * a0 + a1 * a1 + a2 * a2;
    };

    uint32_t k_need = KTOP;
    uint32_t b1 = 0, b2 = 0, b3 = 0;

    #define RUN_PASS(BIN_EXPR, PRED_EXPR, OUT_B)                               \
    {                                                                          \
        for (int i2 = tid; i2 < 2048; i2 += 256) hist[i2] = 0;                 \
        __syncthreads();                                                       \
        for (uint32_t i = tid; i < n; i += 256) {                              \
            uint32_t uv = __float_as_uint(getv(i));                            \
            (void)uv;                                                          \
            if (PRED_EXPR) atomicAdd(&hist[(BIN_EXPR)], 1u);                   \
        }                                                                      \
        __syncthreads();                                                       \
        /* hierarchical inclusive suffix-sum over 2048 bins */                 \
        uint32_t loc[8];                                                       \
        {                                                                      \
            int base8 = tid * 8;                                               \
            uint32_t run = 0;                                                  \
            for (int j = 7; j >= 0; --j) { run += hist[base8 + j]; loc[j] = run; } \
        }                                                                      \
        uint32_t tot = loc[0];                                                 \
        uint32_t scan = tot;                                                   \
        for (int off = 1; off < 64; off <<= 1) {                               \
            uint32_t v = __shfl_down(scan, off, 64);                           \
            if (lane + off < 64) scan += v;                                    \
        }                                                                      \
        if (lane == 0) wtmp[wave] = scan;   /* wave total */                   \
        __syncthreads();                                                       \
        uint32_t wabove = 0;                                                   \
        for (int w = wave + 1; w < 4; ++w) wabove += wtmp[w];                  \
        uint32_t add = (scan - tot) + wabove;                                  \
        {                                                                      \
            int base8 = tid * 8;                                               \
            for (int j = 0; j < 8; ++j) sufx[base8 + j] = loc[j] + add;        \
        }                                                                      \
        __syncthreads();                                                       \
        {                                                                      \
            int base8 = tid * 8;                                               \
            for (int j = 0; j < 8; ++j) {                                      \
                int i2 = base8 + j;                                            \
                uint32_t Si = sufx[i2];                                        \
                uint32_t Sn = (i2 + 1 < 2048) ? sufx[i2 + 1] : 0;              \
                if (Si >= k_need && Sn < k_need) {                             \
                    bcast[0] = (uint32_t)i2;                                   \
                    bcast[1] = k_need - Sn;                                    \
                }                                                              \
            }                                                                  \
        }                                                                      \
        __syncthreads();                                                       \
        OUT_B  = bcast[0];                                                     \
        k_need = bcast[1];                                                     \
        __syncthreads();                                                       \
    }

    RUN_PASS((uv >> 21), true, b1)
    RUN_PASS(((uv >> 10) & 0x7FFu), ((uv >> 21) == b1), b2)
    {
        uint32_t prefix21 = (b1 << 11) | b2;
        RUN_PASS((uv & 0x3FFu), ((uv >> 10) == prefix21), b3)
    }
    #undef RUN_PASS

    const uint32_t T  = (b1 << 21) | (b2 << 10) | b3;
    const float    tv = __uint_as_float(T);

    float    s = 0.0f;
    uint32_t c = 0;
    for (uint32_t i = tid; i < n; i += 256) {
        uint32_t uv = __float_as_uint(getv(i));
        if (uv > T) { s += __uint_as_float(uv); c += 1u; }
    }
    for (int off = 32; off > 0; off >>= 1) {
        s += __shfl_down(s, off, 64);
        c += __shfl_down(c, off, 64);
    }
    if (lane == 0) { wsumS[wave] = s; wcntS[wave] = c; }
    __syncthreads();
    if (tid == 0) {
        float    S = 0.0f;
        uint32_t C = 0;
        for (int w = 0; w < 4; ++w) { S += wsumS[w]; C += wcntS[w]; }
        partials[b] = S + (float)(KTOP - C) * tv;
    }
}

// ---------------------------------------------------------------------------
// Kernel 3: mean of 64 per-batch top-k sums -> scalar
// ---------------------------------------------------------------------------
__global__ void finalize_kernel(const float* __restrict__ partials,
                                float* __restrict__ out)
{
    float v = partials[threadIdx.x];
    for (int off = 32; off > 0; off >>= 1)
        v += __shfl_down(v, off, 64);
    if (threadIdx.x == 0)
        out[0] = v / (float)(BATCH * KTOP);
}

extern "C" void kernel_launch(void* const* d_in, const int* in_sizes, int n_in,
                              void* d_out, int out_size, void* d_ws, size_t ws_size,
                              hipStream_t stream)
{
    const float* pred   = (const float*)d_in[0];
    const float* target = (const float*)d_in[1];
    float* out = (float*)d_out;

    uint32_t* cnt      = (uint32_t*)d_ws;                           // 64 * CNT_STRIDE u32
    float*    partials = (float*)((char*)d_ws + BATCH * CNT_STRIDE * 4);  // 64 f32
    float*    cand     = (float*)((char*)d_ws + BATCH * CNT_STRIDE * 4 + 256);
    const size_t need  = BATCH * CNT_STRIDE * 4 + 256 + (size_t)BATCH * HW * sizeof(float);

    if (ws_size >= need) {
        hipMemsetAsync(cnt, 0, BATCH * CNT_STRIDE * sizeof(uint32_t), stream);
        fused_diff_compact<<<4096, 256, 0, stream>>>(pred, target, cand, cnt);
        select_sum<<<BATCH, 256, 0, stream>>>(cand, cnt, pred, target, partials);
    } else {
        select_sum<<<BATCH, 256, 0, stream>>>(nullptr, nullptr, pred, target, partials);
    }
    finalize_kernel<<<1, 64, 0, stream>>>(partials, out);
}

// Round 4
// 39.911 us; speedup vs baseline: 14.3982x; 1.0315x over previous
//
#include <hip/hip_runtime.h>
#include <hip/hip_bf16.h>
#include <stdint.h>

#define HW 65536
#define BATCH 64
#define KTOP 200
#define TLOW 16.0f      // candidate pre-filter: P(diff >= 16) ~ 4.6% for 2*chi2(3)
#define NSLOT 256       // fixed candidate slots per K1 block (mean ~47, hard max 1024 -> fallback)
#define NBLK_PER_B 64   // K1 blocks per batch
#define CLS_MAX 8192    // K2 LDS candidate capacity

// ---------------------------------------------------------------------------
// Kernel 1: fused diff + threshold compaction, ATOMIC-FREE.
// Block = 1024 elements of one batch. Candidates compacted in LDS, then
// written to this block's PRIVATE slot region + plain-store count.
// ---------------------------------------------------------------------------
__global__ __launch_bounds__(256) void fused_diff_compact(
    const float* __restrict__ pred,
    const float* __restrict__ target,
    float* __restrict__ cand,        // [4096][NSLOT]
    uint32_t* __restrict__ bcnt)     // [4096]
{
    __shared__ float    sbuf[1024];
    __shared__ uint32_t scnt;

    const int tid  = threadIdx.x;
    const int lane = tid & 63;
    if (tid == 0) scnt = 0;
    __syncthreads();

    const int b   = blockIdx.x >> 6;
    const int blk = blockIdx.x & 63;
    const int i   = blk * 256 + tid;       // float4 index within batch [0,16384)

    const float4* p = (const float4*)pred;
    const float4* t = (const float4*)target;
    long base = (long)b * 49152 + i;       // 3 * 16384
    float4 p0 = p[base], p1 = p[base + 16384], p2 = p[base + 32768];
    float4 t0 = t[base], t1 = t[base + 16384], t2 = t[base + 32768];

    float d[4];
    {
        float a0 = t0.x - p0.x, a1 = t1.x - p1.x, a2 = t2.x - p2.x;
        d[0] = a0 * a0 + a1 * a1 + a2 * a2;
    }
    {
        float a0 = t0.y - p0.y, a1 = t1.y - p1.y, a2 = t2.y - p2.y;
        d[1] = a0 * a0 + a1 * a1 + a2 * a2;
    }
    {
        float a0 = t0.z - p0.z, a1 = t1.z - p1.z, a2 = t2.z - p2.z;
        d[2] = a0 * a0 + a1 * a1 + a2 * a2;
    }
    {
        float a0 = t0.w - p0.w, a1 = t1.w - p1.w, a2 = t2.w - p2.w;
        d[3] = a0 * a0 + a1 * a1 + a2 * a2;
    }

    #pragma unroll
    for (int j = 0; j < 4; ++j) {
        bool pr = d[j] >= TLOW;
        unsigned long long mask = __ballot(pr);
        if (mask) {                                   // wave-uniform
            uint32_t c = (uint32_t)__popcll(mask);
            uint32_t wb = 0;
            if (lane == 0) wb = atomicAdd(&scnt, c);  // LDS atomic only (on-CU)
            wb = __shfl(wb, 0, 64);
            if (pr) {
                uint32_t rank = (uint32_t)__popcll(mask & ((1ull << lane) - 1ull));
                sbuf[wb + rank] = d[j];
            }
        }
    }
    __syncthreads();

    const uint32_t nloc = scnt;
    if (tid == 0) bcnt[blockIdx.x] = nloc;            // plain store, no zero needed
    float* cb = cand + (long)blockIdx.x * NSLOT;
    const uint32_t nw = nloc < NSLOT ? nloc : NSLOT;
    for (uint32_t k = tid; k < nw; k += 256)
        cb[k] = sbuf[k];
}

// ---------------------------------------------------------------------------
// Kernel 2: one block (256 thr) per batch. Gather candidates from the 64
// sub-block slots into LDS (wave-scan offsets, no atomics), then exact
// 3-pass radix select + top-KTOP sum. Fallback recomputes full row exactly.
// ---------------------------------------------------------------------------
__global__ __launch_bounds__(256) void select_sum(
    const float* __restrict__ cand,      // may be null -> always fallback
    const uint32_t* __restrict__ bcnt,
    const float* __restrict__ pred,
    const float* __restrict__ target,
    float* __restrict__ partials)
{
    __shared__ uint32_t hist[2048];
    __shared__ uint32_t sufx[2048];
    __shared__ float    cls[CLS_MAX];
    __shared__ uint32_t scounts[64];
    __shared__ uint32_t soff[64];
    __shared__ uint32_t meta[2];         // {total, bad}
    __shared__ uint32_t bcast[2];
    __shared__ uint32_t wtmp[4];
    __shared__ float    wsumS[4];
    __shared__ uint32_t wcntS[4];

    const int b    = blockIdx.x;
    const int tid  = threadIdx.x;
    const int lane = tid & 63;
    const int wave = tid >> 6;

    // ---- read per-sub-block counts, wave-0 exclusive scan ----
    if (cand) {
        if (tid < 64) {
            uint32_t c = bcnt[b * NBLK_PER_B + tid];
            scounts[tid] = c;
            uint32_t scan = c;
            for (int off = 1; off < 64; off <<= 1) {
                uint32_t v = __shfl_up(scan, off, 64);
                if (lane >= off) scan += v;
            }
            soff[tid] = scan - c;                      // exclusive
            if (tid == 63) meta[0] = scan;             // total
            uint32_t ovf = __ballot(c > NSLOT) ? 1u : 0u;
            if (tid == 0) meta[1] = ovf;
        }
    } else if (tid == 0) {
        meta[0] = 0; meta[1] = 1;
    }
    __syncthreads();

    const uint32_t total = meta[0];
    const bool fb = (meta[1] != 0) || (total < KTOP) || (total > CLS_MAX);
    const uint32_t n = fb ? HW : total;

    // ---- gather candidates into LDS (wave w handles 16 sub-blocks) ----
    if (!fb) {
        for (int jj = 0; jj < 16; ++jj) {
            int j = wave * 16 + jj;
            uint32_t c   = scounts[j];
            uint32_t off = soff[j];
            const float* src = cand + (long)(b * NBLK_PER_B + j) * NSLOT;
            for (uint32_t k = lane; k < c; k += 64)
                cls[off + k] = src[k];
        }
    }
    __syncthreads();

    const float* pb = pred   + (long)b * 3 * HW;
    const float* tb = target + (long)b * 3 * HW;

    auto getv = [&](uint32_t i) -> float {
        if (!fb) return cls[i];
        float a0 = tb[i] - pb[i];
        float a1 = tb[HW + i] - pb[HW + i];
        float a2 = tb[2 * HW + i] - pb[2 * HW + i];
        return a0 * a0 + a1 * a1 + a2 * a2;
    };

    uint32_t k_need = KTOP;
    uint32_t b1 = 0, b2 = 0, b3 = 0;

    #define RUN_PASS(BIN_EXPR, PRED_EXPR, OUT_B)                               \
    {                                                                          \
        for (int i2 = tid; i2 < 2048; i2 += 256) hist[i2] = 0;                 \
        __syncthreads();                                                       \
        for (uint32_t i = tid; i < n; i += 256) {                              \
            uint32_t uv = __float_as_uint(getv(i));                            \
            (void)uv;                                                          \
            if (PRED_EXPR) atomicAdd(&hist[(BIN_EXPR)], 1u);                   \
        }                                                                      \
        __syncthreads();                                                       \
        uint32_t loc[8];                                                       \
        {                                                                      \
            int base8 = tid * 8;                                               \
            uint32_t run = 0;                                                  \
            for (int j = 7; j >= 0; --j) { run += hist[base8 + j]; loc[j] = run; } \
        }                                                                      \
        uint32_t tot = loc[0];                                                 \
        uint32_t scan = tot;                                                   \
        for (int off = 1; off < 64; off <<= 1) {                               \
            uint32_t v = __shfl_down(scan, off, 64);                           \
            if (lane + off < 64) scan += v;                                    \
        }                                                                      \
        if (lane == 0) wtmp[wave] = scan;                                      \
        __syncthreads();                                                       \
        uint32_t wabove = 0;                                                   \
        for (int w = wave + 1; w < 4; ++w) wabove += wtmp[w];                  \
        uint32_t add = (scan - tot) + wabove;                                  \
        {                                                                      \
            int base8 = tid * 8;                                               \
            for (int j = 0; j < 8; ++j) sufx[base8 + j] = loc[j] + add;        \
        }                                                                      \
        __syncthreads();                                                       \
        {                                                                      \
            int base8 = tid * 8;                                               \
            for (int j = 0; j < 8; ++j) {                                      \
                int i2 = base8 + j;                                            \
                uint32_t Si = sufx[i2];                                        \
                uint32_t Sn = (i2 + 1 < 2048) ? sufx[i2 + 1] : 0;              \
                if (Si >= k_need && Sn < k_need) {                             \
                    bcast[0] = (uint32_t)i2;                                   \
                    bcast[1] = k_need - Sn;                                    \
                }                                                              \
            }                                                                  \
        }                                                                      \
        __syncthreads();                                                       \
        OUT_B  = bcast[0];                                                     \
        k_need = bcast[1];                                                     \
        __syncthreads();                                                       \
    }

    RUN_PASS((uv >> 21), true, b1)
    RUN_PASS(((uv >> 10) & 0x7FFu), ((uv >> 21) == b1), b2)
    {
        uint32_t prefix21 = (b1 << 11) | b2;
        RUN_PASS((uv & 0x3FFu), ((uv >> 10) == prefix21), b3)
    }
    #undef RUN_PASS

    const uint32_t T  = (b1 << 21) | (b2 << 10) | b3;
    const float    tv = __uint_as_float(T);

    float    s = 0.0f;
    uint32_t c = 0;
    for (uint32_t i = tid; i < n; i += 256) {
        uint32_t uv = __float_as_uint(getv(i));
        if (uv > T) { s += __uint_as_float(uv); c += 1u; }
    }
    for (int off = 32; off > 0; off >>= 1) {
        s += __shfl_down(s, off, 64);
        c += __shfl_down(c, off, 64);
    }
    if (lane == 0) { wsumS[wave] = s; wcntS[wave] = c; }
    __syncthreads();
    if (tid == 0) {
        float    S = 0.0f;
        uint32_t C = 0;
        for (int w = 0; w < 4; ++w) { S += wsumS[w]; C += wcntS[w]; }
        partials[b] = S + (float)(KTOP - C) * tv;
    }
}

// ---------------------------------------------------------------------------
// Kernel 3: mean of 64 per-batch top-k sums -> scalar
// ---------------------------------------------------------------------------
__global__ void finalize_kernel(const float* __restrict__ partials,
                                float* __restrict__ out)
{
    float v = partials[threadIdx.x];
    for (int off = 32; off > 0; off >>= 1)
        v += __shfl_down(v, off, 64);
    if (threadIdx.x == 0)
        out[0] = v / (float)(BATCH * KTOP);
}

extern "C" void kernel_launch(void* const* d_in, const int* in_sizes, int n_in,
                              void* d_out, int out_size, void* d_ws, size_t ws_size,
                              hipStream_t stream)
{
    const float* pred   = (const float*)d_in[0];
    const float* target = (const float*)d_in[1];
    float* out = (float*)d_out;

    const int nblk = BATCH * NBLK_PER_B;                 // 4096
    uint32_t* bcnt     = (uint32_t*)d_ws;                // 16 KB
    float*    partials = (float*)((char*)d_ws + nblk * 4);          // 256 B
    float*    cand     = (float*)((char*)d_ws + nblk * 4 + 1024);   // 4 MB
    const size_t need  = (size_t)nblk * 4 + 1024 + (size_t)nblk * NSLOT * 4;

    if (ws_size >= need) {
        fused_diff_compact<<<nblk, 256, 0, stream>>>(pred, target, cand, bcnt);
        select_sum<<<BATCH, 256, 0, stream>>>(cand, bcnt, pred, target, partials);
    } else {
        select_sum<<<BATCH, 256, 0, stream>>>(nullptr, nullptr, pred, target, partials);
    }
    finalize_kernel<<<1, 64, 0, stream>>>(partials, out);
}